// Round 4
// baseline (343.030 us; speedup 1.0000x reference)
//
#include <hip/hip_runtime.h>
#include <stdint.h>

#define B_ 32
#define T_ 4096
#define C_ 256
#define N_ (T_*C_)            // 1<<20 elements per sample
#define NB 8192               // top 13 bits of |x| bit pattern: bits[30:18]

// ---- workspace layout (bytes) ----
#define HIST_BYTES (B_*NB*4)             // 1 MB global hist (u32[8192] per sample)
#define UPART_OFF  (HIST_BYTES)          // 2048 floats: per-block usum partials
#define THR_OFF    (UPART_OFF + 2048*4)  // 32 floats

typedef float f32x4 __attribute__((ext_vector_type(4)));

// K1: fused uncertainty partial sums + 13-bit histogram of |s|.
// grid = 2048 blocks (64 per sample) x 512 threads; block = 4096 float4/tensor.
// Depth-2 software pipeline: tile i+2 issued before computing tile i ->
// issue-to-use distance ~2 iterations, 12 loads in flight per wave.
// Histogram (s-only) ordered before MSE (needs t) so the t-wait lands late.
// No atomics for usum: per-block partial stores, summed in K2.
__global__ __launch_bounds__(512, 8) void k1_uncert_hist(
    const float* __restrict__ s, const float* __restrict__ t,
    float* __restrict__ upart, unsigned* __restrict__ ghist)
{
    __shared__ unsigned lhist[4096];          // 16 KB packed u16x2
    __shared__ float part[64*68];             // 17.4 KB; stride 68 -> b128-aligned reads
    __shared__ float wu[8];
    const int tid = threadIdx.x;
    #pragma unroll
    for (int k = tid; k < 4096; k += 512) lhist[k] = 0;
    __syncthreads();

    const int b = blockIdx.x >> 6;                    // 64 blocks per sample
    const size_t base4 = (size_t)blockIdx.x * 4096;   // float4 units
    const f32x4* s4 = (const f32x4*)s + base4;
    const f32x4* t4 = (const f32x4*)t + base4;
    const int lane = tid & 63, wid = tid >> 6;
    const int v0 = wid*128 + lane;                    // float4 offset of slot 0

#define LOADT(n, OFF) \
    f32x4 sa##n = s4[v0 + (OFF)]; \
    f32x4 sb##n = s4[v0 + (OFF) + 64]; \
    f32x4 ta##n = __builtin_nontemporal_load(t4 + v0 + (OFF)); \
    f32x4 tb##n = __builtin_nontemporal_load(t4 + v0 + (OFF) + 64);

#define HIST1(x) { unsigned u = __float_as_uint(x); \
    atomicAdd(&lhist[(u>>19)&0xFFFu], 1u << (((u>>18)&1u)<<4)); }

#define COMP(n, IT) { \
    HIST1(sa##n.x) HIST1(sa##n.y) HIST1(sa##n.z) HIST1(sa##n.w) \
    HIST1(sb##n.x) HIST1(sb##n.y) HIST1(sb##n.z) HIST1(sb##n.w) \
    float dx = sa##n.x-ta##n.x, dy = sa##n.y-ta##n.y, \
          dz = sa##n.z-ta##n.z, dw = sa##n.w-ta##n.w; \
    float sum0 = dx*dx + dy*dy + dz*dz + dw*dw; \
    float ex = sb##n.x-tb##n.x, ey = sb##n.y-tb##n.y, \
          ez = sb##n.z-tb##n.z, ew = sb##n.w-tb##n.w; \
    float sum1 = ex*ex + ey*ey + ez*ez + ew*ew; \
    const int tk = (IT)*16 + wid*2; \
    part[tk*68 + lane]     = sum0; \
    part[(tk+1)*68 + lane] = sum1; }

    LOADT(0, 0)
    LOADT(1, 1024)
    LOADT(2, 2048)
    COMP(0, 0)
    LOADT(3, 3072)
    COMP(1, 1)
    COMP(2, 2)
    COMP(3, 3)
#undef LOADT
#undef HIST1
#undef COMP

    __syncthreads();

    // drain packed hist first: fire-and-forget global atomics overlap the reduce
    unsigned* gh = ghist + (size_t)b * NB;
    #pragma unroll
    for (int w = tid; w < 4096; w += 512) {
        const unsigned pc = lhist[w];
        if (pc) {
            const unsigned lo = pc & 0xFFFFu, hi = pc >> 16;
            if (lo) atomicAdd(&gh[2*w],   lo);
            if (hi) atomicAdd(&gh[2*w+1], hi);
        }
    }

    // block-end token reduce: thread -> token tid>>3, chunk tid&7 (8 floats, 2xb128)
    {
        const int tok = tid >> 3, q = tid & 7;
        const f32x4* pp = (const f32x4*)&part[tok*68 + q*8];
        f32x4 r0 = pp[0], r1 = pp[1];
        float ps = r0.x+r0.y+r0.z+r0.w + r1.x+r1.y+r1.z+r1.w;
        ps += __shfl_xor(ps, 1, 64);
        ps += __shfl_xor(ps, 2, 64);
        ps += __shfl_xor(ps, 4, 64);                 // 8-lane group: full token sum
        float u = fminf(ps * (1.0f/128.0f), 1.0f);   // clip(2*mean,0,1)
        // xor over bits 3..5: one representative lane per 8-lane group ->
        // wave's 8 distinct tokens summed exactly once each
        u += __shfl_xor(u, 8, 64);
        u += __shfl_xor(u, 16, 64);
        u += __shfl_xor(u, 32, 64);
        if (lane == 0) wu[wid] = u;
    }
    __syncthreads();
    if (tid == 0) {
        float a = 0.f;
        #pragma unroll
        for (int w = 0; w < 8; ++w) a += wu[w];
        upart[blockIdx.x] = a;                       // plain store, no atomic
    }
}

// K2: per-sample threshold from histogram; parallel scan + owner search.
// grid = 32 blocks x 256 threads.
__global__ __launch_bounds__(256) void k2_thresh(
    const unsigned* __restrict__ ghist, const float* __restrict__ upart,
    const float* __restrict__ risk, float* __restrict__ thr)
{
    __shared__ unsigned lh[NB];
    __shared__ unsigned sc[256];
    __shared__ float res[2];
    __shared__ float susum;
    const int b = blockIdx.x, tid = threadIdx.x;
    const unsigned* gh = ghist + (size_t)b * NB;
    for (int j = tid; j < NB; j += 256) lh[j] = gh[j];   // coalesced
    if (tid < 64) {                                   // sum the 64 block partials
        float v = upart[b*64 + tid];
        v += __shfl_xor(v, 1, 64);
        v += __shfl_xor(v, 2, 64);
        v += __shfl_xor(v, 4, 64);
        v += __shfl_xor(v, 8, 64);
        v += __shfl_xor(v, 16, 64);
        v += __shfl_xor(v, 32, 64);
        if (tid == 0) susum = v;
    }
    __syncthreads();

    unsigned p = 0;
    #pragma unroll
    for (int k = 0; k < 32; ++k) p += lh[tid*32 + k];
    sc[tid] = p;
    __syncthreads();
    // Hillis-Steele inclusive scan over 256
    #pragma unroll
    for (int d = 1; d < 256; d <<= 1) {
        unsigned v = (tid >= d) ? sc[tid - d] : 0u;
        __syncthreads();
        sc[tid] += v;
        __syncthreads();
    }
    const unsigned incl = sc[tid];
    const unsigned excl = incl - p;

    const float distrust = susum * fmaxf(1.f, risk[b]) * (1.0f/(float)T_);
    const double pq  = 0.99 - 0.09 * (double)distrust;
    const double pos = pq * (double)(N_ - 1);
    const unsigned i0 = (unsigned)pos;
    const float g = (float)(pos - (double)i0);

    #pragma unroll
    for (int r = 0; r < 2; ++r) {
        const unsigned rk = i0 + (unsigned)r;
        if (excl <= rk && rk < incl) {               // exactly one owner
            unsigned cum = excl, cnt = 1;
            int bin = tid*32 + 31;
            #pragma unroll
            for (int k = 0; k < 32; ++k) {
                const unsigned c = lh[tid*32 + k];
                if (cum + c > rk) { bin = tid*32 + k; cnt = c; break; }
                cum += c;
            }
            const float lo = __uint_as_float((unsigned)bin << 18);
            const float hi = __uint_as_float((unsigned)(bin + 1) << 18);
            const unsigned j = rk - cum;             // 0-based rank within bin
            res[r] = lo + ((float)(j + 1) / (float)(cnt + 1)) * (hi - lo);
        }
    }
    __syncthreads();
    if (tid == 0) thr[b] = res[0] + g * (res[1] - res[0]);
}

// K3: clip. grid = 4096 blocks x 256 threads, 8 independent float4 per thread.
__global__ __launch_bounds__(256) void k3_clip(
    const float* __restrict__ s, const float* __restrict__ thr,
    float* __restrict__ out)
{
    const int bid = blockIdx.x;
    const int b = bid >> 7;                          // 128 blocks per sample
    const float t = thr[b];
    const size_t base = (size_t)bid * 2048 + threadIdx.x;
    const f32x4* s4 = (const f32x4*)s;
    f32x4* o4 = (f32x4*)out;

    f32x4 v[8];
    #pragma unroll
    for (int k = 0; k < 8; ++k) v[k] = s4[base + (size_t)k*256];
    #pragma unroll
    for (int k = 0; k < 8; ++k) {
        f32x4 a = v[k];
        a.x = fminf(fmaxf(a.x, -t), t);
        a.y = fminf(fmaxf(a.y, -t), t);
        a.z = fminf(fmaxf(a.z, -t), t);
        a.w = fminf(fmaxf(a.w, -t), t);
        __builtin_nontemporal_store(a, o4 + base + (size_t)k*256);
    }
}

extern "C" void kernel_launch(void* const* d_in, const int* in_sizes, int n_in,
                              void* d_out, int out_size, void* d_ws, size_t ws_size,
                              hipStream_t stream) {
    const float* s    = (const float*)d_in[0];
    const float* t    = (const float*)d_in[1];
    const float* risk = (const float*)d_in[2];
    float* out = (float*)d_out;
    char* ws = (char*)d_ws;

    unsigned* hist  = (unsigned*)(ws);
    float*    upart = (float*)(ws + UPART_OFF);
    float*    thr   = (float*)(ws + THR_OFF);

    // zero global hist only (ws is poisoned 0xAA before each timed launch)
    hipMemsetAsync(ws, 0, HIST_BYTES, stream);

    k1_uncert_hist<<<2048, 512, 0, stream>>>(s, t, upart, hist);
    k2_thresh<<<B_, 256, 0, stream>>>(hist, upart, risk, thr);
    k3_clip<<<4096, 256, 0, stream>>>(s, thr, out);
}

// Round 5
// 336.452 us; speedup vs baseline: 1.0196x; 1.0196x over previous
//
#include <hip/hip_runtime.h>
#include <stdint.h>

#define B_ 32
#define T_ 4096
#define C_ 256
#define N_ (T_*C_)            // 1<<20 elements per sample
#define NB 8192               // top 13 bits of |x| bit pattern: bits[30:18]

// ---- workspace layout (bytes) ----
#define HIST_BYTES (B_*NB*4)             // 1 MB global hist (u32[8192] per sample)
#define UPART_OFF  (HIST_BYTES)          // 2048 floats: per-block usum partials
#define THR_OFF    (UPART_OFF + 2048*4)  // 32 floats

typedef float f32x4 __attribute__((ext_vector_type(4)));

// K1: fused uncertainty partial sums + 13-bit histogram of |s|.
// grid = 2048 blocks (64 per sample) x 512 threads; block = 4096 float4/tensor.
// All 16 global loads (256 B/thread) issued before any compute: true in-flight
// pipeline. REQUIRES the 128-VGPR budget from __launch_bounds__(512,4) --
// (512,8) capped VGPRs at 64 (allocator hit 32) and silently serialized the
// loads, pinning K1 at 83 us across two rounds.
__global__ __launch_bounds__(512, 4) void k1_uncert_hist(
    const float* __restrict__ s, const float* __restrict__ t,
    float* __restrict__ upart, unsigned* __restrict__ ghist)
{
    __shared__ unsigned lhist[4096];          // 16 KB packed u16x2
    __shared__ float part[64*68];             // 17.4 KB; stride 68 -> b128-aligned reads
    __shared__ float wu[8];
    const int tid = threadIdx.x;
    #pragma unroll
    for (int k = tid; k < 4096; k += 512) lhist[k] = 0;
    __syncthreads();

    const int b = blockIdx.x >> 6;                    // 64 blocks per sample
    const size_t base4 = (size_t)blockIdx.x * 4096;   // float4 units
    const f32x4* s4 = (const f32x4*)s + base4;
    const f32x4* t4 = (const f32x4*)t + base4;
    const int lane = tid & 63, wid = tid >> 6;
    const int v0 = wid*128 + lane;                    // float4 offset of slot 0

#define LOADT(n, OFF) \
    f32x4 sa##n = s4[v0 + (OFF)]; \
    f32x4 sb##n = s4[v0 + (OFF) + 64]; \
    f32x4 ta##n = __builtin_nontemporal_load(t4 + v0 + (OFF)); \
    f32x4 tb##n = __builtin_nontemporal_load(t4 + v0 + (OFF) + 64);

#define HIST1(x) { unsigned u = __float_as_uint(x); \
    atomicAdd(&lhist[(u>>19)&0xFFFu], 1u << (((u>>18)&1u)<<4)); }

#define COMP(n, IT) { \
    HIST1(sa##n.x) HIST1(sa##n.y) HIST1(sa##n.z) HIST1(sa##n.w) \
    HIST1(sb##n.x) HIST1(sb##n.y) HIST1(sb##n.z) HIST1(sb##n.w) \
    float dx = sa##n.x-ta##n.x, dy = sa##n.y-ta##n.y, \
          dz = sa##n.z-ta##n.z, dw = sa##n.w-ta##n.w; \
    float sum0 = dx*dx + dy*dy + dz*dz + dw*dw; \
    float ex = sb##n.x-tb##n.x, ey = sb##n.y-tb##n.y, \
          ez = sb##n.z-tb##n.z, ew = sb##n.w-tb##n.w; \
    float sum1 = ex*ex + ey*ey + ez*ez + ew*ew; \
    const int tk = (IT)*16 + wid*2; \
    part[tk*68 + lane]     = sum0; \
    part[(tk+1)*68 + lane] = sum1; }

    // issue ALL loads first: 16 x 16B in flight per thread
    LOADT(0, 0)
    LOADT(1, 1024)
    LOADT(2, 2048)
    LOADT(3, 3072)
    COMP(0, 0)
    COMP(1, 1)
    COMP(2, 2)
    COMP(3, 3)
#undef LOADT
#undef HIST1
#undef COMP

    __syncthreads();

    // drain packed hist first: fire-and-forget global atomics overlap the reduce
    unsigned* gh = ghist + (size_t)b * NB;
    #pragma unroll
    for (int w = tid; w < 4096; w += 512) {
        const unsigned pc = lhist[w];
        if (pc) {
            const unsigned lo = pc & 0xFFFFu, hi = pc >> 16;
            if (lo) atomicAdd(&gh[2*w],   lo);
            if (hi) atomicAdd(&gh[2*w+1], hi);
        }
    }

    // block-end token reduce: thread -> token tid>>3, chunk tid&7 (8 floats, 2xb128)
    {
        const int tok = tid >> 3, q = tid & 7;
        const f32x4* pp = (const f32x4*)&part[tok*68 + q*8];
        f32x4 r0 = pp[0], r1 = pp[1];
        float ps = r0.x+r0.y+r0.z+r0.w + r1.x+r1.y+r1.z+r1.w;
        ps += __shfl_xor(ps, 1, 64);
        ps += __shfl_xor(ps, 2, 64);
        ps += __shfl_xor(ps, 4, 64);                 // 8-lane group: full token sum
        float u = fminf(ps * (1.0f/128.0f), 1.0f);   // clip(2*mean,0,1)
        // xor over bits 3..5: one representative lane per 8-lane group ->
        // wave's 8 distinct tokens summed exactly once each
        u += __shfl_xor(u, 8, 64);
        u += __shfl_xor(u, 16, 64);
        u += __shfl_xor(u, 32, 64);
        if (lane == 0) wu[wid] = u;
    }
    __syncthreads();
    if (tid == 0) {
        float a = 0.f;
        #pragma unroll
        for (int w = 0; w < 8; ++w) a += wu[w];
        upart[blockIdx.x] = a;                       // plain store, no atomic
    }
}

// K2: per-sample threshold from histogram; parallel scan + owner search.
// grid = 32 blocks x 256 threads.
__global__ __launch_bounds__(256) void k2_thresh(
    const unsigned* __restrict__ ghist, const float* __restrict__ upart,
    const float* __restrict__ risk, float* __restrict__ thr)
{
    __shared__ unsigned lh[NB];
    __shared__ unsigned sc[256];
    __shared__ float res[2];
    __shared__ float susum;
    const int b = blockIdx.x, tid = threadIdx.x;
    const unsigned* gh = ghist + (size_t)b * NB;
    for (int j = tid; j < NB; j += 256) lh[j] = gh[j];   // coalesced
    if (tid < 64) {                                   // sum the 64 block partials
        float v = upart[b*64 + tid];
        v += __shfl_xor(v, 1, 64);
        v += __shfl_xor(v, 2, 64);
        v += __shfl_xor(v, 4, 64);
        v += __shfl_xor(v, 8, 64);
        v += __shfl_xor(v, 16, 64);
        v += __shfl_xor(v, 32, 64);
        if (tid == 0) susum = v;
    }
    __syncthreads();

    unsigned p = 0;
    #pragma unroll
    for (int k = 0; k < 32; ++k) p += lh[tid*32 + k];
    sc[tid] = p;
    __syncthreads();
    // Hillis-Steele inclusive scan over 256
    #pragma unroll
    for (int d = 1; d < 256; d <<= 1) {
        unsigned v = (tid >= d) ? sc[tid - d] : 0u;
        __syncthreads();
        sc[tid] += v;
        __syncthreads();
    }
    const unsigned incl = sc[tid];
    const unsigned excl = incl - p;

    const float distrust = susum * fmaxf(1.f, risk[b]) * (1.0f/(float)T_);
    const double pq  = 0.99 - 0.09 * (double)distrust;
    const double pos = pq * (double)(N_ - 1);
    const unsigned i0 = (unsigned)pos;
    const float g = (float)(pos - (double)i0);

    #pragma unroll
    for (int r = 0; r < 2; ++r) {
        const unsigned rk = i0 + (unsigned)r;
        if (excl <= rk && rk < incl) {               // exactly one owner
            unsigned cum = excl, cnt = 1;
            int bin = tid*32 + 31;
            #pragma unroll
            for (int k = 0; k < 32; ++k) {
                const unsigned c = lh[tid*32 + k];
                if (cum + c > rk) { bin = tid*32 + k; cnt = c; break; }
                cum += c;
            }
            const float lo = __uint_as_float((unsigned)bin << 18);
            const float hi = __uint_as_float((unsigned)(bin + 1) << 18);
            const unsigned j = rk - cum;             // 0-based rank within bin
            res[r] = lo + ((float)(j + 1) / (float)(cnt + 1)) * (hi - lo);
        }
    }
    __syncthreads();
    if (tid == 0) thr[b] = res[0] + g * (res[1] - res[0]);
}

// K3: clip. grid = 4096 blocks x 256 threads, 8 independent float4 per thread.
__global__ __launch_bounds__(256) void k3_clip(
    const float* __restrict__ s, const float* __restrict__ thr,
    float* __restrict__ out)
{
    const int bid = blockIdx.x;
    const int b = bid >> 7;                          // 128 blocks per sample
    const float t = thr[b];
    const size_t base = (size_t)bid * 2048 + threadIdx.x;
    const f32x4* s4 = (const f32x4*)s;
    f32x4* o4 = (f32x4*)out;

    f32x4 v[8];
    #pragma unroll
    for (int k = 0; k < 8; ++k) v[k] = s4[base + (size_t)k*256];
    #pragma unroll
    for (int k = 0; k < 8; ++k) {
        f32x4 a = v[k];
        a.x = fminf(fmaxf(a.x, -t), t);
        a.y = fminf(fmaxf(a.y, -t), t);
        a.z = fminf(fmaxf(a.z, -t), t);
        a.w = fminf(fmaxf(a.w, -t), t);
        __builtin_nontemporal_store(a, o4 + base + (size_t)k*256);
    }
}

extern "C" void kernel_launch(void* const* d_in, const int* in_sizes, int n_in,
                              void* d_out, int out_size, void* d_ws, size_t ws_size,
                              hipStream_t stream) {
    const float* s    = (const float*)d_in[0];
    const float* t    = (const float*)d_in[1];
    const float* risk = (const float*)d_in[2];
    float* out = (float*)d_out;
    char* ws = (char*)d_ws;

    unsigned* hist  = (unsigned*)(ws);
    float*    upart = (float*)(ws + UPART_OFF);
    float*    thr   = (float*)(ws + THR_OFF);

    // zero global hist only (ws is poisoned 0xAA before each timed launch)
    hipMemsetAsync(ws, 0, HIST_BYTES, stream);

    k1_uncert_hist<<<2048, 512, 0, stream>>>(s, t, upart, hist);
    k2_thresh<<<B_, 256, 0, stream>>>(hist, upart, risk, thr);
    k3_clip<<<4096, 256, 0, stream>>>(s, thr, out);
}